// Round 1
// baseline (219.057 us; speedup 1.0000x reference)
//
#include <hip/hip_runtime.h>

// DigitCaps with O=1: routing softmax over a single out-capsule is identity,
// so the whole reference reduces to
//   s[b,v]  = sum_{i,d} W[i,v,d] * x[b,i,d]        (M=32, N=512, K=32768 GEMM)
//   out     = s * sqrt(sq)/(1+sq),  sq = sum_v s^2  (per-b squash)
// and both tuple outputs (t, outputs) are identical [32,1,512] tensors.

#define NB 32
#define NI 4096
#define NV 512
#define ND 8
#define XSTRIDE (NI * ND)  // 32768 floats per batch row of x

// ---------------------------------------------------------------------------
// Kernel 1: per-(i-chunk, v) partial sums.
// lane = v. Each thread accumulates all 32 batches in registers (32 VGPRs),
// so every W element is read from global exactly once, coalesced (32 B/lane).
// x[b,i,d] is wave-uniform -> scalar loads (s_load) feed the SGPR operand of
// v_fma_f32: the VALU stream stays essentially pure FMA, no LDS needed.
// ---------------------------------------------------------------------------
template <int ICHUNK>
__global__ __launch_bounds__(256, 2) void caps_partial_kernel(
    const float* __restrict__ x, const float* __restrict__ W,
    float* __restrict__ partial)
{
    const int t  = threadIdx.x;
    const int vb = blockIdx.x & 1;
    const int ic = blockIdx.x >> 1;
    const int v  = vb * 256 + t;
    const int i0 = ic * ICHUNK;

    float acc[NB];
#pragma unroll
    for (int b = 0; b < NB; ++b) acc[b] = 0.0f;

    const float4* wp = (const float4*)(W + ((size_t)i0 * NV + v) * ND);
    float4 w0 = wp[0];   // software prefetch: W row for current i
    float4 w1 = wp[1];

    for (int ii = 0; ii < ICHUNK; ++ii) {
        const float wreg[8] = {w0.x, w0.y, w0.z, w0.w, w1.x, w1.y, w1.z, w1.w};
        if (ii + 1 < ICHUNK) {          // prefetch next i's W row (uniform branch)
            wp += (NV * ND) / 4;        // stride V*D floats = 1024 float4
            w0 = wp[0];
            w1 = wp[1];
        }
        const float* xp = x + (size_t)(i0 + ii) * ND;
#pragma unroll
        for (int b = 0; b < NB; ++b) {
            float a = acc[b];
#pragma unroll
            for (int d = 0; d < ND; ++d)
                a = fmaf(wreg[d], xp[(size_t)b * XSTRIDE + d], a);  // x: s_load (uniform)
            acc[b] = a;
        }
    }

#pragma unroll
    for (int b = 0; b < NB; ++b)
        partial[((size_t)ic * NB + b) * NV + v] = acc[b];  // coalesced per b
}

// ---------------------------------------------------------------------------
// Kernel 2: reduce partials over chunks, squash per batch, write both outputs.
// Block b handles one batch; thread t owns v = t and v = t + 256.
// ---------------------------------------------------------------------------
__global__ __launch_bounds__(256) void caps_squash_kernel(
    const float* __restrict__ partial, float* __restrict__ out, int nchunk)
{
    const int b = blockIdx.x;
    const int t = threadIdx.x;

    float s0 = 0.0f, s1 = 0.0f;
    for (int ic = 0; ic < nchunk; ++ic) {
        const float* p = partial + ((size_t)ic * NB + b) * NV;
        s0 += p[t];
        s1 += p[t + 256];
    }

    float sq = s0 * s0 + s1 * s1;
#pragma unroll
    for (int off = 32; off > 0; off >>= 1)
        sq += __shfl_xor(sq, off, 64);

    __shared__ float red[4];
    const int wave = t >> 6;
    const int lane = t & 63;
    if (lane == 0) red[wave] = sq;
    __syncthreads();
    const float tot = red[0] + red[1] + red[2] + red[3];

    // squash factor: sq/( (1+sq)*sqrt(sq) ) == sqrt(sq)/(1+sq)
    const float factor = tot / ((1.0f + tot) * sqrtf(tot));

    const size_t o = (size_t)b * NV;
    const float r0 = s0 * factor;
    const float r1 = s1 * factor;
    out[o + t]                   = r0;  // output 0: t  [B,1,V]
    out[o + t + 256]             = r1;
    out[NB * NV + o + t]         = r0;  // output 1: outputs [B,O,V] (identical)
    out[NB * NV + o + t + 256]   = r1;
}

extern "C" void kernel_launch(void* const* d_in, const int* in_sizes, int n_in,
                              void* d_out, int out_size, void* d_ws, size_t ws_size,
                              hipStream_t stream) {
    const float* x = (const float*)d_in[0];   // [32, 4096, 8]
    const float* W = (const float*)d_in[1];   // [1, 4096, 512, 8]
    float* out     = (float*)d_out;           // 2 x [32,1,512] concatenated
    float* partial = (float*)d_ws;

    // partial buffer: nchunk * 32 * 512 floats. Pick chunking to fit ws.
    const size_t need16 = (size_t)(NI / 16) * NB * NV * sizeof(float);  // 16 MB
    const size_t need64 = (size_t)(NI / 64) * NB * NV * sizeof(float);  //  4 MB

    if (ws_size >= need16) {
        const int nchunk = NI / 16;                       // 256 chunks
        caps_partial_kernel<16><<<nchunk * 2, 256, 0, stream>>>(x, W, partial);
        caps_squash_kernel<<<NB, 256, 0, stream>>>(partial, out, nchunk);
    } else if (ws_size >= need64) {
        const int nchunk = NI / 64;                       // 64 chunks
        caps_partial_kernel<64><<<nchunk * 2, 256, 0, stream>>>(x, W, partial);
        caps_squash_kernel<<<NB, 256, 0, stream>>>(partial, out, nchunk);
    } else {
        const int nchunk = NI / 256;                      // 16 chunks (1 MB)
        caps_partial_kernel<256><<<nchunk * 2, 256, 0, stream>>>(x, W, partial);
        caps_squash_kernel<<<NB, 256, 0, stream>>>(partial, out, nchunk);
    }
}

// Round 2
// 190.024 us; speedup vs baseline: 1.1528x; 1.1528x over previous
//
#include <hip/hip_runtime.h>

// DigitCaps with O=1: routing softmax over one out-capsule is identity, so
// the reference reduces to
//   s[b,v]  = sum_{i,d} W[i,v,d] * x[b,i,d]        (M=32, N=512, K=32768 GEMM)
//   out     = s * sqrt(sq)/(1+sq),  sq = sum_v s^2  (per-b squash)
// Both tuple outputs (t, outputs) are identical [32,1,512] tensors.
//
// R2: R1's acc[32]-per-thread spilled to scratch (VGPR_Count=28, VALUBusy 8%).
// Now b is split across the block's 4 waves -> 8 accumulators/thread (cannot
// spill), and phase 2 is a proper 32x512 parallel reduce.

#define NB 32
#define NI 4096
#define NV 512
#define ND 8
#define XSTRIDE (NI * ND)  // floats per batch row of x
#define IC 32              // i's per chunk -> nc = 128 chunks

// ---------------------------------------------------------------------------
// Phase 1: partial[ic][b][v] = sum over i-chunk of W[i,v,:].x[b,i,:]
// Block: 256 threads = 4 waves. wave w -> b in [8w, 8w+8). lane -> v in tile.
// Grid: (8 v-tiles) x (128 i-chunks) = 1024 blocks.
// W: 32 B/lane float4 pair, prefetched 1 iter deep (read once from HBM/L3,
// 4x wave redundancy served by L1). x: wave-uniform float4 pair per b,
// prefetched 1 b deep (4 MB total, L2-resident; broadcast loads).
// ---------------------------------------------------------------------------
__global__ __launch_bounds__(256) void caps_partial(
    const float* __restrict__ x, const float* __restrict__ W,
    float* __restrict__ partial)
{
    const int t    = threadIdx.x;
    const int lane = t & 63;
    const int wave = t >> 6;
    const int vg   = blockIdx.x & 7;
    const int ic   = blockIdx.x >> 3;
    const int v    = vg * 64 + lane;
    const int b0   = wave * 8;
    const int i0   = ic * IC;

    float acc[8];
#pragma unroll
    for (int b = 0; b < 8; ++b) acc[b] = 0.0f;

    const float4* wp = (const float4*)(W + ((size_t)i0 * NV + v) * ND);
    float4 w0 = wp[0], w1 = wp[1];  // prefetch current i

    const float* xbase = x + (size_t)b0 * XSTRIDE + (size_t)i0 * ND;

    for (int ii = 0; ii < IC; ++ii) {
        const float4 cw0 = w0, cw1 = w1;
        if (ii + 1 < IC) {                 // uniform branch: prefetch next i
            wp += (NV * ND) / 4;
            w0 = wp[0];
            w1 = wp[1];
        }
        const float* xp = xbase + (size_t)ii * ND;
        float4 x0 = ((const float4*)xp)[0];  // prefetch b=0
        float4 x1 = ((const float4*)xp)[1];
#pragma unroll
        for (int b = 0; b < 8; ++b) {
            const float4 cx0 = x0, cx1 = x1;
            if (b + 1 < 8) {               // prefetch next b
                const float* xn = xp + (size_t)(b + 1) * XSTRIDE;
                x0 = ((const float4*)xn)[0];
                x1 = ((const float4*)xn)[1];
            }
            float a = acc[b];
            a = fmaf(cw0.x, cx0.x, a);
            a = fmaf(cw0.y, cx0.y, a);
            a = fmaf(cw0.z, cx0.z, a);
            a = fmaf(cw0.w, cx0.w, a);
            a = fmaf(cw1.x, cx1.x, a);
            a = fmaf(cw1.y, cx1.y, a);
            a = fmaf(cw1.z, cx1.z, a);
            a = fmaf(cw1.w, cx1.w, a);
            acc[b] = a;
        }
    }

#pragma unroll
    for (int b = 0; b < 8; ++b)
        partial[((size_t)ic * NB + b0 + b) * NV + v] = acc[b];  // coalesced in v
}

// ---------------------------------------------------------------------------
// Phase 2: reduce chunks, squash per batch, write both outputs.
// Grid: 32 blocks (one per b) x 512 threads (one per v).
// ---------------------------------------------------------------------------
__global__ __launch_bounds__(512) void caps_finish(
    const float* __restrict__ partial, float* __restrict__ out, int nc)
{
    const int b = blockIdx.x;
    const int v = threadIdx.x;

    float s = 0.0f;
    for (int ic = 0; ic < nc; ++ic)
        s += partial[((size_t)ic * NB + b) * NV + v];  // coalesced in v

    float sq = s * s;
#pragma unroll
    for (int off = 32; off > 0; off >>= 1)
        sq += __shfl_xor(sq, off, 64);

    __shared__ float red[8];
    if ((v & 63) == 0) red[v >> 6] = sq;
    __syncthreads();
    float tot = 0.0f;
#pragma unroll
    for (int wv = 0; wv < 8; ++wv) tot += red[wv];

    // squash factor: sq/((1+sq)*sqrt(sq)) == sqrt(sq)/(1+sq)
    const float factor = sqrtf(tot) / (1.0f + tot);
    const float r = s * factor;

    out[(size_t)b * NV + v]           = r;  // output 0: t       [B,1,V]
    out[NB * NV + (size_t)b * NV + v] = r;  // output 1: outputs [B,O,V]
}

extern "C" void kernel_launch(void* const* d_in, const int* in_sizes, int n_in,
                              void* d_out, int out_size, void* d_ws, size_t ws_size,
                              hipStream_t stream) {
    const float* x = (const float*)d_in[0];   // [32, 4096, 8]
    const float* W = (const float*)d_in[1];   // [1, 4096, 512, 8]
    float* out     = (float*)d_out;           // 2 x [32,1,512] concatenated
    float* partial = (float*)d_ws;

    const int nc = NI / IC;                   // 128 chunks
    // partial buffer: nc*32*512*4 = 8 MB (R1 confirmed ws >= 16 MB)
    caps_partial<<<8 * nc, 256, 0, stream>>>(x, W, partial);
    caps_finish<<<NB, 512, 0, stream>>>(partial, out, nc);
}

// Round 3
// 133.640 us; speedup vs baseline: 1.6392x; 1.4219x over previous
//
#include <hip/hip_runtime.h>

// DigitCaps with O=1: routing softmax over one out-capsule is identity, so
// the reference reduces to
//   s[b,v]  = sum_{i,d} W[i,v,d] * x[b,i,d]        (M=32, N=512, K=32768 GEMM)
//   out     = s * sqrt(sq)/(1+sq),  sq = sum_v s^2  (per-b squash)
// Both tuple outputs (t, outputs) are identical [32,1,512] tensors.
//
// R3 changes vs R2 (which was latency-bound: VALUBusy 24%, finish ~100us):
//  - b-group now comes from blockIdx -> x loads are BLOCK-uniform, read-only,
//    __restrict__ -> compiler emits s_load (scalar pipe), freeing VMEM slots.
//  - W prefetched 2 iterations deep (~300cyc) against stream-miss latency.
//  - phase 2 is a 2-stage tree reduce with unrolled independent loads (MLP),
//    replacing the 128-long serial load chain that cost ~100us.

#define NB 32
#define NI 4096
#define NV 512
#define ND 8
#define XSTRIDE (NI * ND)   // floats per batch row of x
#define IC 32               // i's per chunk
#define NC (NI / IC)        // 128 chunks
#define NC8 (NC / 8)        // 16 second-stage groups

// ---------------------------------------------------------------------------
// Phase 1: partial[ic][b][v] = sum over i-chunk of W[i,v,:].x[b,i,:]
// Grid: bg(4) x vhalf(2) x ic(128) = 1024 blocks, 256 threads.
// Thread t -> v = vhalf*256 + t; every thread accumulates 8 batches
// (b = bg*8 .. bg*8+7). W: 32 B/lane float4 pair, 2-deep prefetch, read
// coalesced (2 KB/wave). x: block-uniform scalar loads (s_load_dwordx8).
// ---------------------------------------------------------------------------
__global__ __launch_bounds__(256) void caps_partial(
    const float* __restrict__ x, const float* __restrict__ W,
    float* __restrict__ partial)
{
    const int t  = threadIdx.x;
    const int bx = blockIdx.x;
    const int bg = bx & 3;          // fastest-varying: 4 bgroups of same W tile
    const int vh = (bx >> 2) & 1;   // co-scheduled -> L3-temporal W reuse
    const int ic = bx >> 3;
    const int v  = vh * 256 + t;
    const int b0 = bg * 8;
    const int i0 = ic * IC;

    float acc[8];
#pragma unroll
    for (int b = 0; b < 8; ++b) acc[b] = 0.0f;

    // 2-deep rolling W prefetch
    const float4* wp = (const float4*)(W + ((size_t)i0 * NV + v) * ND);
    float4 wa0 = wp[0], wa1 = wp[1];
    wp += (NV * ND) / 4;
    float4 wb0 = wp[0], wb1 = wp[1];

    const float* xb = x + (size_t)b0 * XSTRIDE + (size_t)i0 * ND;

    for (int ii = 0; ii < IC; ++ii) {
        const float4 cw0 = wa0, cw1 = wa1;
        wa0 = wb0; wa1 = wb1;
        if (ii + 2 < IC) {              // uniform branch: fetch ii+2's W row
            wp += (NV * ND) / 4;
            wb0 = wp[0];
            wb1 = wp[1];
        }
        const float* xp = xb + (size_t)ii * ND;   // block-uniform address
#pragma unroll
        for (int b = 0; b < 8; ++b) {
            const float* xq = xp + (size_t)b * XSTRIDE;  // uniform -> s_load
            float a = acc[b];
            a = fmaf(cw0.x, xq[0], a);
            a = fmaf(cw0.y, xq[1], a);
            a = fmaf(cw0.z, xq[2], a);
            a = fmaf(cw0.w, xq[3], a);
            a = fmaf(cw1.x, xq[4], a);
            a = fmaf(cw1.y, xq[5], a);
            a = fmaf(cw1.z, xq[6], a);
            a = fmaf(cw1.w, xq[7], a);
            acc[b] = a;
        }
    }

#pragma unroll
    for (int b = 0; b < 8; ++b)
        partial[((size_t)ic * NB + b0 + b) * NV + v] = acc[b];  // coalesced in v
}

// ---------------------------------------------------------------------------
// Phase 2a: tree reduce, 8 chunks -> 1.  Grid: NC8(16) x NB(32) = 512 blocks,
// 512 threads (one per v). 8 independent coalesced loads per thread (MLP).
// ---------------------------------------------------------------------------
__global__ __launch_bounds__(512) void caps_reduce8(
    const float* __restrict__ partial, float* __restrict__ partial2)
{
    const int v = threadIdx.x;
    const int b = blockIdx.x & 31;
    const int g = blockIdx.x >> 5;       // 0..NC8-1

    const float* p = partial + ((size_t)(g * 8) * NB + b) * NV + v;
    float s = 0.0f;
#pragma unroll
    for (int j = 0; j < 8; ++j)
        s += p[(size_t)j * NB * NV];

    partial2[((size_t)g * NB + b) * NV + v] = s;
}

// ---------------------------------------------------------------------------
// Phase 2b: final reduce over NC8 groups + squash + write both outputs.
// Grid: 32 blocks (one per b) x 512 threads (one per v).
// ---------------------------------------------------------------------------
__global__ __launch_bounds__(512) void caps_finish(
    const float* __restrict__ partial2, float* __restrict__ out)
{
    const int v = threadIdx.x;
    const int b = blockIdx.x;

    float s = 0.0f;
#pragma unroll
    for (int g = 0; g < NC8; ++g)        // fully unrolled: 16 independent loads
        s += partial2[((size_t)g * NB + b) * NV + v];

    float sq = s * s;
#pragma unroll
    for (int off = 32; off > 0; off >>= 1)
        sq += __shfl_xor(sq, off, 64);

    __shared__ float red[8];
    if ((v & 63) == 0) red[v >> 6] = sq;
    __syncthreads();
    float tot = 0.0f;
#pragma unroll
    for (int wv = 0; wv < 8; ++wv) tot += red[wv];

    // squash factor: sq/((1+sq)*sqrt(sq)) == sqrt(sq)/(1+sq)
    const float factor = sqrtf(tot) / (1.0f + tot);
    const float r = s * factor;

    out[(size_t)b * NV + v]           = r;  // output 0: t       [B,1,V]
    out[NB * NV + (size_t)b * NV + v] = r;  // output 1: outputs [B,O,V]
}

extern "C" void kernel_launch(void* const* d_in, const int* in_sizes, int n_in,
                              void* d_out, int out_size, void* d_ws, size_t ws_size,
                              hipStream_t stream) {
    const float* x = (const float*)d_in[0];   // [32, 4096, 8]
    const float* W = (const float*)d_in[1];   // [1, 4096, 512, 8]
    float* out     = (float*)d_out;           // 2 x [32,1,512] concatenated

    float* partial  = (float*)d_ws;                           // 8 MB
    float* partial2 = partial + (size_t)NC * NB * NV;         // +1 MB (ws >= 16 MB)

    caps_partial<<<4 * 2 * NC, 256, 0, stream>>>(x, W, partial);
    caps_reduce8<<<NC8 * NB, 512, 0, stream>>>(partial, partial2);
    caps_finish<<<NB, 512, 0, stream>>>(partial2, out);
}